// Round 10
// baseline (705.883 us; speedup 1.0000x reference)
//
#include <hip/hip_runtime.h>

// GAT 3-layer forward. CSR-by-dst aggregation v3: two edges per load-round
// (lanes 0-31 = edge i, lanes 32-63 = edge i+1, 8B/lane), w computed once per
// (edge,head) by producer lanes and shfl-broadcast; fp16 gather tables; fast exp.
// fp16x2-split MFMA GEMM with fused node_att epilogue.
// segment_max dropped: cancels exactly in alpha = e/denom; logits are O(+-3) here.

#define NEG_SLOPE 0.2f

typedef __attribute__((ext_vector_type(8))) _Float16 half8v;
typedef __attribute__((ext_vector_type(4))) _Float16 half4v;
typedef __attribute__((ext_vector_type(4))) float f32x4;

__device__ __forceinline__ float lrelu(float v) { return v > 0.f ? v : NEG_SLOPE * v; }

struct hf2 { _Float16 hi, lo; };
__device__ __forceinline__ hf2 split_f16(float f)
{
    hf2 r;
    r.hi = (_Float16)f;
    r.lo = (_Float16)(f - (float)r.hi);
    return r;
}

// ---------------- diagnostics: workspace overflow sentinel ----------------
__global__ void fill_sentinel(float* __restrict__ out, int n)
{
    int i = blockIdx.x * blockDim.x + threadIdx.x;
    if (i < n) out[i] = 1e30f;
}

// ---------------- edge-index dtype detection (int64 vs int32) ----------------
__global__ void detect_idx64(const int* __restrict__ ei, int* __restrict__ flag)
{
    __shared__ int anynz;
    if (threadIdx.x == 0) anynz = 0;
    __syncthreads();
    int v = ei[2 * threadIdx.x + 1];   // high words if int64 (all values < 2^31)
    if (v != 0) atomicOr(&anynz, 1);
    __syncthreads();
    if (threadIdx.x == 0) flag[0] = (anynz == 0) ? 1 : 0;   // 1 => int64
}

// prep_edges: convert to int32 + degree histogram + per-edge local offset (fused)
__global__ void prep_edges(const void* __restrict__ ei, const int* __restrict__ flag,
                           int* __restrict__ src32, int* __restrict__ dst32,
                           int* __restrict__ deg, int* __restrict__ loc, int E)
{
    int e = blockIdx.x * blockDim.x + threadIdx.x;
    if (e >= E) return;
    int s, d;
    if (flag[0]) { s = (int)((const long long*)ei)[e]; d = (int)((const long long*)ei)[E + e]; }
    else         { s = ((const int*)ei)[e];            d = ((const int*)ei)[E + e]; }
    src32[e] = s;
    dst32[e] = d;
    loc[e] = atomicAdd(&deg[d], 1);
}

__global__ __launch_bounds__(256)
void scanA(const int* __restrict__ deg, int* __restrict__ rowptr,
           int* __restrict__ bsum, int N)
{
    __shared__ int part[256];
    const int t = threadIdx.x;
    const int base = blockIdx.x * 1024 + t * 4;
    int v[4];
    #pragma unroll
    for (int j = 0; j < 4; ++j) v[j] = (base + j < N) ? deg[base + j] : 0;
    int s = v[0] + v[1] + v[2] + v[3];
    part[t] = s;
    __syncthreads();
    #pragma unroll
    for (int off = 1; off < 256; off <<= 1) {
        int p = (t >= off) ? part[t - off] : 0;
        __syncthreads();
        part[t] += p;
        __syncthreads();
    }
    int run = (t == 0) ? 0 : part[t - 1];
    #pragma unroll
    for (int j = 0; j < 4; ++j) {
        if (base + j < N) rowptr[base + j] = run;
        run += v[j];
    }
    if (t == 255) bsum[blockIdx.x] = part[255];
}

__global__ __launch_bounds__(1024)
void scanB(int* __restrict__ bsum, int nb)
{
    __shared__ int s[1024];
    int t = threadIdx.x;
    s[t] = (t < nb) ? bsum[t] : 0;
    __syncthreads();
    for (int off = 1; off < 1024; off <<= 1) {
        int p = (t >= off) ? s[t - off] : 0;
        __syncthreads();
        s[t] += p;
        __syncthreads();
    }
    if (t < nb) bsum[t] = (t == 0) ? 0 : s[t - 1];
}

__global__ __launch_bounds__(256)
void scanC(int* __restrict__ rowptr, const int* __restrict__ bsum, int N, int E)
{
    const int base = blockIdx.x * 1024 + threadIdx.x * 4;
    const int off = bsum[blockIdx.x];
    #pragma unroll
    for (int j = 0; j < 4; ++j)
        if (base + j < N) rowptr[base + j] += off;
    if (blockIdx.x == 0 && threadIdx.x == 0) rowptr[N] = E;
}

__global__ void fill_csr(const int* __restrict__ src32, const int* __restrict__ dst32,
                         const int* __restrict__ loc, const int* __restrict__ rowptr,
                         int* __restrict__ csr_src, int E)
{
    int e = blockIdx.x * blockDim.x + threadIdx.x;
    if (e >= E) return;
    csr_src[rowptr[dst32[e]] + loc[e]] = src32[e];
}

// ---------------- f32 -> fp16 hi/lo converts ----------------
__global__ void convert_hilo(const float* __restrict__ in, _Float16* __restrict__ hi,
                             _Float16* __restrict__ lo, long long n4)
{
    long long t = (long long)blockIdx.x * blockDim.x + threadIdx.x;
    if (t >= n4) return;
    float4 v = *(const float4*)&in[t * 4];
    hf2 a = split_f16(v.x), b = split_f16(v.y), c = split_f16(v.z), d = split_f16(v.w);
    half4v h, l;
    h.x = a.hi; h.y = b.hi; h.z = c.hi; h.w = d.hi;
    l.x = a.lo; l.y = b.lo; l.z = c.lo; l.w = d.lo;
    *(half4v*)&hi[t * 4] = h;
    *(half4v*)&lo[t * 4] = l;
}

// W chunk [128 k][128 n] -> transposed Wt_hi/lo [n][k] fp16
__global__ __launch_bounds__(256)
void convert_wt(const float* __restrict__ W, _Float16* __restrict__ wthi,
                _Float16* __restrict__ wtlo, int ldw, int wcol0)
{
    int t = blockIdx.x * 256 + threadIdx.x;   // 16384 threads
    int k = t >> 7, n = t & 127;
    float v = W[(long long)k * ldw + wcol0 + n];
    hf2 r = split_f16(v);
    wthi[n * 128 + k] = r.hi;
    wtlo[n * 128 + k] = r.lo;
}

// ---------------- MFMA GEMM + fused node_att epilogue ----------------
// h[M][128] fp16 = (Ahi+Alo) @ (Wthi+Wtlo)^T; block = 4 waves, wave = 16 rows x 128 cols.
// A frag: lane row = l&15, k = (l>>4)*8..+7. B frag: Wt row n = nf*16 + (l&15).
// D: row = (l>>4)*4 + r, col = l&15 (dtype-independent layout, m89/m121).
// Epilogue: als/ald[row,h] = <C_row_head, a_flat> via in-register dot + 16-lane shfl tree.
template<int HPC>
__global__ __launch_bounds__(256)
void gemm_mfma(const _Float16* __restrict__ Ahi, const _Float16* __restrict__ Alo,
               const _Float16* __restrict__ Wthi, const _Float16* __restrict__ Wtlo,
               _Float16* __restrict__ Chi,
               const float* __restrict__ aS, const float* __restrict__ aD,
               float* __restrict__ als, float* __restrict__ ald, int M)
{
    const int tid = threadIdx.x;
    const int wave = tid >> 6, lane = tid & 63;
    const int l15 = lane & 15, lk = lane >> 4;      // 0..3
    const int m0 = blockIdx.x * 64 + wave * 16;
    int mrow = m0 + l15;
    if (mrow >= M) mrow = M - 1;                     // clamp; stores guarded below

    f32x4 acc[8];
    #pragma unroll
    for (int i = 0; i < 8; ++i) acc[i] = (f32x4){0.f, 0.f, 0.f, 0.f};

    #pragma unroll
    for (int kt = 0; kt < 4; ++kt) {
        const int k = kt * 32 + lk * 8;
        half8v ah = *(const half8v*)&Ahi[(long long)mrow * 128 + k];
        half8v al = *(const half8v*)&Alo[(long long)mrow * 128 + k];
        #pragma unroll
        for (int nf = 0; nf < 8; ++nf) {
            half8v bh = *(const half8v*)&Wthi[(nf * 16 + l15) * 128 + k];
            half8v bl = *(const half8v*)&Wtlo[(nf * 16 + l15) * 128 + k];
            acc[nf] = __builtin_amdgcn_mfma_f32_16x16x32_f16(ah, bh, acc[nf], 0, 0, 0);
            acc[nf] = __builtin_amdgcn_mfma_f32_16x16x32_f16(ah, bl, acc[nf], 0, 0, 0);
            acc[nf] = __builtin_amdgcn_mfma_f32_16x16x32_f16(al, bh, acc[nf], 0, 0, 0);
        }
    }

    // store h (fp16)
    #pragma unroll
    for (int r = 0; r < 4; ++r) {
        int gm = m0 + lk * 4 + r;
        if (gm >= M) continue;
        #pragma unroll
        for (int nf = 0; nf < 8; ++nf)
            Chi[(long long)gm * 128 + nf * 16 + l15] = (_Float16)acc[nf][r];
    }

    // fused node_att: col = nf*16 + l15, head = nf / (8/HPC)
    float asv[8], adv[8];
    #pragma unroll
    for (int nf = 0; nf < 8; ++nf) {
        asv[nf] = aS[nf * 16 + l15];
        adv[nf] = aD[nf * 16 + l15];
    }
    constexpr int NFH = 8 / HPC;   // acc regs per head
    #pragma unroll
    for (int r = 0; r < 4; ++r) {
        #pragma unroll
        for (int h = 0; h < HPC; ++h) {
            float ps = 0.f, pd = 0.f;
            #pragma unroll
            for (int q = 0; q < NFH; ++q) {
                int nf = h * NFH + q;
                ps += acc[nf][r] * asv[nf];
                pd += acc[nf][r] * adv[nf];
            }
            #pragma unroll
            for (int m = 1; m < 16; m <<= 1) {
                ps += __shfl_xor(ps, m);
                pd += __shfl_xor(pd, m);
            }
            if (l15 == 0) {
                int gm = m0 + lk * 4 + r;
                if (gm < M) {
                    als[gm * HPC + h] = ps;
                    ald[gm * HPC + h] = pd;
                }
            }
        }
    }
}

// ---------------- aggregate v3: one wave per dst node, 2 edges per round ----------------
// ROW = HL*C = 128. sub = lane&31 owns 4 cols q=4*sub; half = lane>>5 selects edge parity.
// Per batch of 8 edges (4 rounds x 2): producer lanes compute w once; sv/w broadcast via
// shfl; each half-wave accumulates its edge stream into f32 vx[4]/dn; merged via
// shfl_xor(32) at the end.
// concat (MEAN=false): elu(vec/denom + bias) -> fp16 hi/lo (next GEMM input)
// mean   (MEAN=true) : per-head divide, 0.25x, shfl_xor(16) head-pair sum, lanes 0-15
//                      store float4 (+ prev out + bias if ACCUM).
template<int C, int HL, bool MEAN, bool ACCUM>
__global__ __launch_bounds__(256)
void gat_aggregate(const int* __restrict__ rowptr, const int* __restrict__ csr_src,
                   const float* __restrict__ als, const float* __restrict__ ald,
                   const _Float16* __restrict__ h16, const float* __restrict__ bias,
                   float* __restrict__ out,
                   _Float16* __restrict__ ohi, _Float16* __restrict__ olo, int N)
{
    constexpr int ROW = HL * C;            // 128
    constexpr int LOG2HL = (HL == 4) ? 2 : 1;
    const int d = (blockIdx.x * blockDim.x + threadIdx.x) >> 6;
    const int lane = threadIdx.x & 63;
    if (d >= N) return;
    const int sub = lane & 31;
    const int half = lane >> 5;
    const int q = sub * 4;                 // first of 4 owned cols
    const int chd = q / C;                 // consumer head (all 4 cols same head)

    const int myh = lane & (HL - 1);       // producer assignment
    const int myi = lane >> LOG2HL;
    const float ald_mine = ald[d * HL + myh];

    float vx0 = 0.f, vx1 = 0.f, vx2 = 0.f, vx3 = 0.f, dn = 0.f;
    if (half == 0) {
        const float wself = __expf(lrelu(als[d * HL + chd] + ald[d * HL + chd]));
        half4v hs = *(const half4v*)&h16[(unsigned)d * ROW + q];
        dn = wself;
        vx0 = wself * (float)hs.x; vx1 = wself * (float)hs.y;
        vx2 = wself * (float)hs.z; vx3 = wself * (float)hs.w;
    }

    const int e0 = rowptr[d], e1 = rowptr[d + 1];
    for (int base = e0; base < e1; base += 8) {
        int sv_mine = 0;
        float w_mine = 0.f;
        if (lane < 8 * HL) {               // producers: one (edge, head) each
            int ee = base + myi;
            sv_mine = csr_src[ee < e1 ? ee : e1 - 1];
            float a = als[sv_mine * HL + myh] + ald_mine;
            w_mine = (ee < e1) ? __expf(lrelu(a)) : 0.f;
        }
        int srefs[4];
        #pragma unroll
        for (int r = 0; r < 4; ++r)
            srefs[r] = __shfl(sv_mine, (2 * r + half) * HL, 64);
        half4v hb[4];
        #pragma unroll
        for (int r = 0; r < 4; ++r)
            hb[r] = *(const half4v*)&h16[(unsigned)srefs[r] * ROW + q];
        #pragma unroll
        for (int r = 0; r < 4; ++r) {
            float wv = __shfl(w_mine, (2 * r + half) * HL + chd, 64);
            dn += wv;
            vx0 += wv * (float)hb[r].x;
            vx1 += wv * (float)hb[r].y;
            vx2 += wv * (float)hb[r].z;
            vx3 += wv * (float)hb[r].w;
        }
    }
    // merge the two edge streams
    vx0 += __shfl_xor(vx0, 32); vx1 += __shfl_xor(vx1, 32);
    vx2 += __shfl_xor(vx2, 32); vx3 += __shfl_xor(vx3, 32);
    dn  += __shfl_xor(dn, 32);
    if (half != 0) return;

    const float inv = 1.f / dn;
    if (!MEAN) {
        float o[4] = {vx0 * inv, vx1 * inv, vx2 * inv, vx3 * inv};
        half4v hi4, lo4;
        #pragma unroll
        for (int k = 0; k < 4; ++k) {
            float v = o[k] + bias[q + k];
            v = v > 0.f ? v : __expf(v) - 1.f;
            hf2 s = split_f16(v);
            if (k == 0) { hi4.x = s.hi; lo4.x = s.lo; }
            else if (k == 1) { hi4.y = s.hi; lo4.y = s.lo; }
            else if (k == 2) { hi4.z = s.hi; lo4.z = s.lo; }
            else { hi4.w = s.hi; lo4.w = s.lo; }
        }
        *(half4v*)&ohi[(unsigned)d * ROW + q] = hi4;
        *(half4v*)&olo[(unsigned)d * ROW + q] = lo4;
    } else {
        // per-head divide first, then head-pair sum (C=64, HL=2)
        float m0 = 0.25f * vx0 * inv, m1 = 0.25f * vx1 * inv;
        float m2 = 0.25f * vx2 * inv, m3 = 0.25f * vx3 * inv;
        m0 += __shfl_xor(m0, 16); m1 += __shfl_xor(m1, 16);
        m2 += __shfl_xor(m2, 16); m3 += __shfl_xor(m3, 16);
        if (sub < 16) {
            float* op = &out[(unsigned)d * C + q];
            if (ACCUM) {
                float4 prev = *(const float4*)op;
                m0 += prev.x + bias[q + 0];
                m1 += prev.y + bias[q + 1];
                m2 += prev.z + bias[q + 2];
                m3 += prev.w + bias[q + 3];
            }
            *(float4*)op = make_float4(m0, m1, m2, m3);
        }
    }
}

extern "C" void kernel_launch(void* const* d_in, const int* in_sizes, int n_in,
                              void* d_out, int out_size, void* d_ws, size_t ws_size,
                              hipStream_t stream)
{
    const float* x      = (const float*)d_in[0];
    const void*  ei     = d_in[1];
    const float* W1     = (const float*)d_in[2];
    const float* a_src1 = (const float*)d_in[3];
    const float* a_dst1 = (const float*)d_in[4];
    const float* b1     = (const float*)d_in[5];
    const float* W2     = (const float*)d_in[6];
    const float* a_src2 = (const float*)d_in[7];
    const float* a_dst2 = (const float*)d_in[8];
    const float* b2     = (const float*)d_in[9];
    const float* W3     = (const float*)d_in[10];
    const float* a_src3 = (const float*)d_in[11];
    const float* a_dst3 = (const float*)d_in[12];
    const float* b3     = (const float*)d_in[13];

    const int N = in_sizes[0] / 128;
    const int E = in_sizes[1] / 2;

    char* w = (char*)d_ws;
    auto alloc = [&](size_t bytes) {
        char* p = w;
        w += (bytes + 255) & ~(size_t)255;
        return p;
    };
    int*      flag    = (int*)     alloc(256);
    int*      deg     = (int*)     alloc((size_t)N * 4);
    int*      rowptr  = (int*)     alloc((size_t)(N + 1) * 4);
    int*      bsum    = (int*)     alloc(1024 * 4);
    int*      src32   = (int*)     alloc((size_t)E * 4);
    int*      dst32   = (int*)     alloc((size_t)E * 4);
    int*      loc     = (int*)     alloc((size_t)E * 4);
    int*      csr_src = (int*)     alloc((size_t)E * 4);
    _Float16* hhi     = (_Float16*)alloc((size_t)N * 128 * 2);
    _Float16* xhi     = (_Float16*)alloc((size_t)N * 128 * 2);
    _Float16* xlo     = (_Float16*)alloc((size_t)N * 128 * 2);
    float*    als     = (float*)   alloc((size_t)N * 4 * 4);
    float*    ald     = (float*)   alloc((size_t)N * 4 * 4);
    _Float16* wthi    = (_Float16*)alloc(128 * 128 * 2);
    _Float16* wtlo    = (_Float16*)alloc(128 * 128 * 2);
    if ((size_t)(w - (char*)d_ws) > ws_size) {
        fill_sentinel<<<(out_size + 255) / 256, 256, 0, stream>>>((float*)d_out, out_size);
        return;
    }

    const int gb = 256;
    const int nb1024 = (N + 1023) / 1024;
    const int mb = (N + 63) / 64;                  // gemm blocks (64 rows each)
    const int ab = (N * 64 + gb - 1) / gb;         // aggregate: 1 wave/node
    auto blocks = [&](long long tot) { return (int)((tot + gb - 1) / gb); };

    // ---------------- CSR build ----------------
    detect_idx64<<<1, 256, 0, stream>>>((const int*)ei, flag);
    (void)hipMemsetAsync(deg, 0, (size_t)N * 4, stream);
    prep_edges<<<blocks(E), gb, 0, stream>>>(ei, flag, src32, dst32, deg, loc, E);
    scanA<<<nb1024, gb, 0, stream>>>(deg, rowptr, bsum, N);
    scanB<<<1, 1024, 0, stream>>>(bsum, nb1024);
    scanC<<<nb1024, gb, 0, stream>>>(rowptr, bsum, N, E);
    fill_csr<<<blocks(E), gb, 0, stream>>>(src32, dst32, loc, rowptr, csr_src, E);

    // layer-1 input -> fp16 hi/lo
    convert_hilo<<<blocks((long long)N * 32), gb, 0, stream>>>(x, xhi, xlo, (long long)N * 32);

    // ---------------- layer 1 ----------------
    convert_wt<<<64, gb, 0, stream>>>(W1, wthi, wtlo, 128, 0);
    gemm_mfma<4><<<mb, gb, 0, stream>>>(xhi, xlo, wthi, wtlo, hhi,
                                        a_src1, a_dst1, als, ald, N);
    gat_aggregate<32, 4, false, false><<<ab, gb, 0, stream>>>(
        rowptr, csr_src, als, ald, hhi, b1, nullptr, xhi, xlo, N);

    // ---------------- layer 2 ----------------
    convert_wt<<<64, gb, 0, stream>>>(W2, wthi, wtlo, 128, 0);
    gemm_mfma<4><<<mb, gb, 0, stream>>>(xhi, xlo, wthi, wtlo, hhi,
                                        a_src2, a_dst2, als, ald, N);
    gat_aggregate<32, 4, false, false><<<ab, gb, 0, stream>>>(
        rowptr, csr_src, als, ald, hhi, b2, nullptr, xhi, xlo, N);

    // ---------------- layer 3: two head-pair chunks into d_out ----------------
    convert_wt<<<64, gb, 0, stream>>>(W3, wthi, wtlo, 256, 0);
    gemm_mfma<2><<<mb, gb, 0, stream>>>(xhi, xlo, wthi, wtlo, hhi,
                                        a_src3, a_dst3, als, ald, N);
    gat_aggregate<64, 2, true, false><<<ab, gb, 0, stream>>>(
        rowptr, csr_src, als, ald, hhi, b3, (float*)d_out, nullptr, nullptr, N);

    convert_wt<<<64, gb, 0, stream>>>(W3, wthi, wtlo, 256, 128);
    gemm_mfma<2><<<mb, gb, 0, stream>>>(xhi, xlo, wthi, wtlo, hhi,
                                        a_src3 + 128, a_dst3 + 128, als, ald, N);
    gat_aggregate<64, 2, true, true><<<ab, gb, 0, stream>>>(
        rowptr, csr_src, als, ald, hhi, b3, (float*)d_out, nullptr, nullptr, N);
}

// Round 11
// 698.777 us; speedup vs baseline: 1.0102x; 1.0102x over previous
//
#include <hip/hip_runtime.h>

// GAT 3-layer forward. CSR-by-dst aggregation v2 (4B/lane gather, producer/shfl-broadcast
// w), 8-copy XCD-partitioned degree histogram (kills cross-XCD atomic line bounce),
// fp16x2-split MFMA GEMM with fused node_att epilogue, fp16 gather tables, fast exp.
// segment_max dropped: cancels exactly in alpha = e/denom; logits are O(+-3) here.

#define NEG_SLOPE 0.2f

typedef __attribute__((ext_vector_type(8))) _Float16 half8v;
typedef __attribute__((ext_vector_type(4))) _Float16 half4v;
typedef __attribute__((ext_vector_type(2))) _Float16 half2v;
typedef __attribute__((ext_vector_type(4))) float f32x4;

__device__ __forceinline__ float lrelu(float v) { return v > 0.f ? v : NEG_SLOPE * v; }

struct hf2 { _Float16 hi, lo; };
__device__ __forceinline__ hf2 split_f16(float f)
{
    hf2 r;
    r.hi = (_Float16)f;
    r.lo = (_Float16)(f - (float)r.hi);
    return r;
}

// ---------------- diagnostics: workspace overflow sentinel ----------------
__global__ void fill_sentinel(float* __restrict__ out, int n)
{
    int i = blockIdx.x * blockDim.x + threadIdx.x;
    if (i < n) out[i] = 1e30f;
}

// ---------------- edge-index dtype detection (int64 vs int32) ----------------
__global__ void detect_idx64(const int* __restrict__ ei, int* __restrict__ flag)
{
    __shared__ int anynz;
    if (threadIdx.x == 0) anynz = 0;
    __syncthreads();
    int v = ei[2 * threadIdx.x + 1];   // high words if int64 (all values < 2^31)
    if (v != 0) atomicOr(&anynz, 1);
    __syncthreads();
    if (threadIdx.x == 0) flag[0] = (anynz == 0) ? 1 : 0;   // 1 => int64
}

// prep_edges: int32 convert + 8-copy degree histogram (copy = blockIdx&7) + local offset
__global__ void prep_edges(const void* __restrict__ ei, const int* __restrict__ flag,
                           int* __restrict__ src32, int* __restrict__ dst32,
                           int* __restrict__ deg8, int* __restrict__ loc, int N, int E)
{
    int e = blockIdx.x * blockDim.x + threadIdx.x;
    if (e >= E) return;
    int s, d;
    if (flag[0]) { s = (int)((const long long*)ei)[e]; d = (int)((const long long*)ei)[E + e]; }
    else         { s = ((const int*)ei)[e];            d = ((const int*)ei)[E + e]; }
    src32[e] = s;
    dst32[e] = d;
    loc[e] = atomicAdd(&deg8[(blockIdx.x & 7) * N + d], 1);
}

// reduce8: deg[d] = sum_k deg8[k][d]; deg8[k][d] <- exclusive prefix (in place)
__global__ void reduce8(int* __restrict__ deg8, int* __restrict__ deg, int N)
{
    int d = blockIdx.x * blockDim.x + threadIdx.x;
    if (d >= N) return;
    int s = 0;
    #pragma unroll
    for (int k = 0; k < 8; ++k) {
        int v = deg8[k * N + d];
        deg8[k * N + d] = s;
        s += v;
    }
    deg[d] = s;
}

__global__ __launch_bounds__(256)
void scanA(const int* __restrict__ deg, int* __restrict__ rowptr,
           int* __restrict__ bsum, int N)
{
    __shared__ int part[256];
    const int t = threadIdx.x;
    const int base = blockIdx.x * 1024 + t * 4;
    int v[4];
    #pragma unroll
    for (int j = 0; j < 4; ++j) v[j] = (base + j < N) ? deg[base + j] : 0;
    int s = v[0] + v[1] + v[2] + v[3];
    part[t] = s;
    __syncthreads();
    #pragma unroll
    for (int off = 1; off < 256; off <<= 1) {
        int p = (t >= off) ? part[t - off] : 0;
        __syncthreads();
        part[t] += p;
        __syncthreads();
    }
    int run = (t == 0) ? 0 : part[t - 1];
    #pragma unroll
    for (int j = 0; j < 4; ++j) {
        if (base + j < N) rowptr[base + j] = run;
        run += v[j];
    }
    if (t == 255) bsum[blockIdx.x] = part[255];
}

__global__ __launch_bounds__(1024)
void scanB(int* __restrict__ bsum, int nb)
{
    __shared__ int s[1024];
    int t = threadIdx.x;
    s[t] = (t < nb) ? bsum[t] : 0;
    __syncthreads();
    for (int off = 1; off < 1024; off <<= 1) {
        int p = (t >= off) ? s[t - off] : 0;
        __syncthreads();
        s[t] += p;
        __syncthreads();
    }
    if (t < nb) bsum[t] = (t == 0) ? 0 : s[t - 1];
}

__global__ __launch_bounds__(256)
void scanC(int* __restrict__ rowptr, const int* __restrict__ bsum, int N, int E)
{
    const int base = blockIdx.x * 1024 + threadIdx.x * 4;
    const int off = bsum[blockIdx.x];
    #pragma unroll
    for (int j = 0; j < 4; ++j)
        if (base + j < N) rowptr[base + j] += off;
    if (blockIdx.x == 0 && threadIdx.x == 0) rowptr[N] = E;
}

// fill_csr: pure scatter; pos = rowptr[d] + off8[k][d] + loc[e], k = blockIdx&7
__global__ void fill_csr(const int* __restrict__ src32, const int* __restrict__ dst32,
                         const int* __restrict__ loc, const int* __restrict__ rowptr,
                         const int* __restrict__ deg8, int* __restrict__ csr_src,
                         int N, int E)
{
    int e = blockIdx.x * blockDim.x + threadIdx.x;
    if (e >= E) return;
    int d = dst32[e];
    csr_src[rowptr[d] + deg8[(blockIdx.x & 7) * N + d] + loc[e]] = src32[e];
}

// ---------------- f32 -> fp16 hi/lo converts ----------------
__global__ void convert_hilo(const float* __restrict__ in, _Float16* __restrict__ hi,
                             _Float16* __restrict__ lo, long long n4)
{
    long long t = (long long)blockIdx.x * blockDim.x + threadIdx.x;
    if (t >= n4) return;
    float4 v = *(const float4*)&in[t * 4];
    hf2 a = split_f16(v.x), b = split_f16(v.y), c = split_f16(v.z), d = split_f16(v.w);
    half4v h, l;
    h.x = a.hi; h.y = b.hi; h.z = c.hi; h.w = d.hi;
    l.x = a.lo; l.y = b.lo; l.z = c.lo; l.w = d.lo;
    *(half4v*)&hi[t * 4] = h;
    *(half4v*)&lo[t * 4] = l;
}

// W chunk [128 k][128 n] -> transposed Wt_hi/lo [n][k] fp16
__global__ __launch_bounds__(256)
void convert_wt(const float* __restrict__ W, _Float16* __restrict__ wthi,
                _Float16* __restrict__ wtlo, int ldw, int wcol0)
{
    int t = blockIdx.x * 256 + threadIdx.x;   // 16384 threads
    int k = t >> 7, n = t & 127;
    float v = W[(long long)k * ldw + wcol0 + n];
    hf2 r = split_f16(v);
    wthi[n * 128 + k] = r.hi;
    wtlo[n * 128 + k] = r.lo;
}

// ---------------- MFMA GEMM + fused node_att epilogue ----------------
// h[M][128] fp16 = (Ahi+Alo) @ (Wthi+Wtlo)^T; block = 4 waves, wave = 16 rows x 128 cols.
// A frag: lane row = l&15, k = (l>>4)*8..+7. B frag: Wt row n = nf*16 + (l&15).
// D: row = (l>>4)*4 + r, col = l&15 (dtype-independent layout, m89/m121).
// Epilogue: als/ald[row,h] = <C_row_head, a_flat> via in-register dot + 16-lane shfl tree.
template<int HPC>
__global__ __launch_bounds__(256)
void gemm_mfma(const _Float16* __restrict__ Ahi, const _Float16* __restrict__ Alo,
               const _Float16* __restrict__ Wthi, const _Float16* __restrict__ Wtlo,
               _Float16* __restrict__ Chi,
               const float* __restrict__ aS, const float* __restrict__ aD,
               float* __restrict__ als, float* __restrict__ ald, int M)
{
    const int tid = threadIdx.x;
    const int wave = tid >> 6, lane = tid & 63;
    const int l15 = lane & 15, lk = lane >> 4;      // 0..3
    const int m0 = blockIdx.x * 64 + wave * 16;
    int mrow = m0 + l15;
    if (mrow >= M) mrow = M - 1;                     // clamp; stores guarded below

    f32x4 acc[8];
    #pragma unroll
    for (int i = 0; i < 8; ++i) acc[i] = (f32x4){0.f, 0.f, 0.f, 0.f};

    #pragma unroll
    for (int kt = 0; kt < 4; ++kt) {
        const int k = kt * 32 + lk * 8;
        half8v ah = *(const half8v*)&Ahi[(long long)mrow * 128 + k];
        half8v al = *(const half8v*)&Alo[(long long)mrow * 128 + k];
        #pragma unroll
        for (int nf = 0; nf < 8; ++nf) {
            half8v bh = *(const half8v*)&Wthi[(nf * 16 + l15) * 128 + k];
            half8v bl = *(const half8v*)&Wtlo[(nf * 16 + l15) * 128 + k];
            acc[nf] = __builtin_amdgcn_mfma_f32_16x16x32_f16(ah, bh, acc[nf], 0, 0, 0);
            acc[nf] = __builtin_amdgcn_mfma_f32_16x16x32_f16(ah, bl, acc[nf], 0, 0, 0);
            acc[nf] = __builtin_amdgcn_mfma_f32_16x16x32_f16(al, bh, acc[nf], 0, 0, 0);
        }
    }

    // store h (fp16)
    #pragma unroll
    for (int r = 0; r < 4; ++r) {
        int gm = m0 + lk * 4 + r;
        if (gm >= M) continue;
        #pragma unroll
        for (int nf = 0; nf < 8; ++nf)
            Chi[(long long)gm * 128 + nf * 16 + l15] = (_Float16)acc[nf][r];
    }

    // fused node_att: col = nf*16 + l15, head = nf / (8/HPC)
    float asv[8], adv[8];
    #pragma unroll
    for (int nf = 0; nf < 8; ++nf) {
        asv[nf] = aS[nf * 16 + l15];
        adv[nf] = aD[nf * 16 + l15];
    }
    constexpr int NFH = 8 / HPC;   // acc regs per head
    #pragma unroll
    for (int r = 0; r < 4; ++r) {
        #pragma unroll
        for (int h = 0; h < HPC; ++h) {
            float ps = 0.f, pd = 0.f;
            #pragma unroll
            for (int q = 0; q < NFH; ++q) {
                int nf = h * NFH + q;
                ps += acc[nf][r] * asv[nf];
                pd += acc[nf][r] * adv[nf];
            }
            #pragma unroll
            for (int m = 1; m < 16; m <<= 1) {
                ps += __shfl_xor(ps, m);
                pd += __shfl_xor(pd, m);
            }
            if (l15 == 0) {
                int gm = m0 + lk * 4 + r;
                if (gm < M) {
                    als[gm * HPC + h] = ps;
                    ald[gm * HPC + h] = pd;
                }
            }
        }
    }
}

// ---------------- aggregate v2: one wave per dst node, shfl-broadcast w ----------------
// ROW = HL*C = 128; lane owns 2 cols at j = lane*2.
// Per batch of 8 edges: lane i*HL+h computes w(edge i, head h) once; sv and w are
// broadcast to all lanes via __shfl. Tail masking folded into the computing lane.
// concat (MEAN=false): elu(vec/denom + bias) -> fp16 hi/lo (next GEMM input)
// mean   (MEAN=true) : out[d] (+)= 0.25 * headpair_sum(vec/denom) (+ bias if ACCUM)
template<int C, int HL, bool MEAN, bool ACCUM>
__global__ __launch_bounds__(256)
void gat_aggregate(const int* __restrict__ rowptr, const int* __restrict__ csr_src,
                   const float* __restrict__ als, const float* __restrict__ ald,
                   const _Float16* __restrict__ h16, const float* __restrict__ bias,
                   float* __restrict__ out,
                   _Float16* __restrict__ ohi, _Float16* __restrict__ olo, int N)
{
    constexpr int ROW = HL * C;            // 128
    constexpr int LOG2HL = (HL == 4) ? 2 : 1;
    const int d = (blockIdx.x * blockDim.x + threadIdx.x) >> 6;
    const int lane = threadIdx.x & 63;
    if (d >= N) return;
    const int j = lane * 2;
    const int hh = j / C;                  // consumer head

    const int myh = lane & (HL - 1);       // producer (edge, head) assignment
    const int myi = lane >> LOG2HL;
    const float ald_mine = ald[d * HL + myh];

    const float ald_d = (HL == 4 && myh == hh) ? ald_mine : ald[d * HL + hh];
    const float wself = __expf(lrelu(als[d * HL + hh] + ald_d));
    float denom = wself;
    half2v hv = *(const half2v*)&h16[(unsigned)d * ROW + j];
    float vx = wself * (float)hv.x, vy = wself * (float)hv.y;

    const int e0 = rowptr[d], e1 = rowptr[d + 1];
    for (int base = e0; base < e1; base += 8) {
        // producer: one (edge, head) per lane (lanes 0..8*HL-1 meaningful)
        int ee = base + myi;
        int sv_mine = csr_src[ee < e1 ? ee : e1 - 1];
        float a = als[sv_mine * HL + myh] + ald_mine;
        float w_mine = (ee < e1) ? __expf(lrelu(a)) : 0.f;

        // broadcast sv, gather rows (batched for ILP), then broadcast w + FMA
        int sref[8];
        half2v hb[8];
        #pragma unroll
        for (int i = 0; i < 8; ++i) sref[i] = __shfl(sv_mine, i * HL, 64);
        #pragma unroll
        for (int i = 0; i < 8; ++i) hb[i] = *(const half2v*)&h16[(unsigned)sref[i] * ROW + j];
        #pragma unroll
        for (int i = 0; i < 8; ++i) {
            float wv = __shfl(w_mine, i * HL + hh, 64);
            denom += wv;
            vx += wv * (float)hb[i].x;
            vy += wv * (float)hb[i].y;
        }
    }
    float inv = 1.f / denom;
    vx *= inv; vy *= inv;

    if (!MEAN) {
        vx += bias[j]; vy += bias[j + 1];
        vx = vx > 0.f ? vx : __expf(vx) - 1.f;
        vy = vy > 0.f ? vy : __expf(vy) - 1.f;
        hf2 rx = split_f16(vx), ry = split_f16(vy);
        half2v hi2, lo2;
        hi2.x = rx.hi; hi2.y = ry.hi;
        lo2.x = rx.lo; lo2.y = ry.lo;
        *(half2v*)&ohi[(unsigned)d * ROW + j] = hi2;
        *(half2v*)&olo[(unsigned)d * ROW + j] = lo2;
    } else {
        // HL=2, C=64: lane l and l+32 hold the same output col for heads 0/1
        vx = 0.25f * vx + __shfl_xor(0.25f * vx, 32);
        vy = 0.25f * vy + __shfl_xor(0.25f * vy, 32);
        if (lane < 32) {
            float* op = &out[(unsigned)d * C + j];
            if (ACCUM) { vx += op[0] + bias[j]; vy += op[1] + bias[j + 1]; }
            *(float2*)op = make_float2(vx, vy);
        }
    }
}

extern "C" void kernel_launch(void* const* d_in, const int* in_sizes, int n_in,
                              void* d_out, int out_size, void* d_ws, size_t ws_size,
                              hipStream_t stream)
{
    const float* x      = (const float*)d_in[0];
    const void*  ei     = d_in[1];
    const float* W1     = (const float*)d_in[2];
    const float* a_src1 = (const float*)d_in[3];
    const float* a_dst1 = (const float*)d_in[4];
    const float* b1     = (const float*)d_in[5];
    const float* W2     = (const float*)d_in[6];
    const float* a_src2 = (const float*)d_in[7];
    const float* a_dst2 = (const float*)d_in[8];
    const float* b2     = (const float*)d_in[9];
    const float* W3     = (const float*)d_in[10];
    const float* a_src3 = (const float*)d_in[11];
    const float* a_dst3 = (const float*)d_in[12];
    const float* b3     = (const float*)d_in[13];

    const int N = in_sizes[0] / 128;
    const int E = in_sizes[1] / 2;

    char* w = (char*)d_ws;
    auto alloc = [&](size_t bytes) {
        char* p = w;
        w += (bytes + 255) & ~(size_t)255;
        return p;
    };
    int*      flag    = (int*)     alloc(256);
    int*      deg8    = (int*)     alloc((size_t)N * 8 * 4);
    int*      deg     = (int*)     alloc((size_t)N * 4);
    int*      rowptr  = (int*)     alloc((size_t)(N + 1) * 4);
    int*      bsum    = (int*)     alloc(1024 * 4);
    int*      src32   = (int*)     alloc((size_t)E * 4);
    int*      dst32   = (int*)     alloc((size_t)E * 4);
    int*      loc     = (int*)     alloc((size_t)E * 4);
    int*      csr_src = (int*)     alloc((size_t)E * 4);
    _Float16* hhi     = (_Float16*)alloc((size_t)N * 128 * 2);
    _Float16* xhi     = (_Float16*)alloc((size_t)N * 128 * 2);
    _Float16* xlo     = (_Float16*)alloc((size_t)N * 128 * 2);
    float*    als     = (float*)   alloc((size_t)N * 4 * 4);
    float*    ald     = (float*)   alloc((size_t)N * 4 * 4);
    _Float16* wthi    = (_Float16*)alloc(128 * 128 * 2);
    _Float16* wtlo    = (_Float16*)alloc(128 * 128 * 2);
    if ((size_t)(w - (char*)d_ws) > ws_size) {
        fill_sentinel<<<(out_size + 255) / 256, 256, 0, stream>>>((float*)d_out, out_size);
        return;
    }

    const int gb = 256;
    const int nb1024 = (N + 1023) / 1024;
    const int mb = (N + 63) / 64;                  // gemm blocks (64 rows each)
    const int ab = (N * 64 + gb - 1) / gb;         // aggregate: 1 wave/node
    auto blocks = [&](long long tot) { return (int)((tot + gb - 1) / gb); };

    // ---------------- CSR build ----------------
    detect_idx64<<<1, 256, 0, stream>>>((const int*)ei, flag);
    (void)hipMemsetAsync(deg8, 0, (size_t)N * 8 * 4, stream);
    prep_edges<<<blocks(E), gb, 0, stream>>>(ei, flag, src32, dst32, deg8, loc, N, E);
    reduce8<<<blocks(N), gb, 0, stream>>>(deg8, deg, N);
    scanA<<<nb1024, gb, 0, stream>>>(deg, rowptr, bsum, N);
    scanB<<<1, 1024, 0, stream>>>(bsum, nb1024);
    scanC<<<nb1024, gb, 0, stream>>>(rowptr, bsum, N, E);
    fill_csr<<<blocks(E), gb, 0, stream>>>(src32, dst32, loc, rowptr, deg8, csr_src, N, E);

    // layer-1 input -> fp16 hi/lo
    convert_hilo<<<blocks((long long)N * 32), gb, 0, stream>>>(x, xhi, xlo, (long long)N * 32);

    // ---------------- layer 1 ----------------
    convert_wt<<<64, gb, 0, stream>>>(W1, wthi, wtlo, 128, 0);
    gemm_mfma<4><<<mb, gb, 0, stream>>>(xhi, xlo, wthi, wtlo, hhi,
                                        a_src1, a_dst1, als, ald, N);
    gat_aggregate<32, 4, false, false><<<ab, gb, 0, stream>>>(
        rowptr, csr_src, als, ald, hhi, b1, nullptr, xhi, xlo, N);

    // ---------------- layer 2 ----------------
    convert_wt<<<64, gb, 0, stream>>>(W2, wthi, wtlo, 128, 0);
    gemm_mfma<4><<<mb, gb, 0, stream>>>(xhi, xlo, wthi, wtlo, hhi,
                                        a_src2, a_dst2, als, ald, N);
    gat_aggregate<32, 4, false, false><<<ab, gb, 0, stream>>>(
        rowptr, csr_src, als, ald, hhi, b2, nullptr, xhi, xlo, N);

    // ---------------- layer 3: two head-pair chunks into d_out ----------------
    convert_wt<<<64, gb, 0, stream>>>(W3, wthi, wtlo, 256, 0);
    gemm_mfma<2><<<mb, gb, 0, stream>>>(xhi, xlo, wthi, wtlo, hhi,
                                        a_src3, a_dst3, als, ald, N);
    gat_aggregate<64, 2, true, false><<<ab, gb, 0, stream>>>(
        rowptr, csr_src, als, ald, hhi, b3, (float*)d_out, nullptr, nullptr, N);

    convert_wt<<<64, gb, 0, stream>>>(W3, wthi, wtlo, 256, 128);
    gemm_mfma<2><<<mb, gb, 0, stream>>>(xhi, xlo, wthi, wtlo, hhi,
                                        a_src3 + 128, a_dst3 + 128, als, ald, N);
    gat_aggregate<64, 2, true, true><<<ab, gb, 0, stream>>>(
        rowptr, csr_src, als, ald, hhi, b3, (float*)d_out, nullptr, nullptr, N);
}